// Round 11
// baseline (827.786 us; speedup 1.0000x reference)
//
#include <hip/hip_runtime.h>
#include <hip/hip_fp16.h>

typedef _Float16 f16x4 __attribute__((ext_vector_type(4)));
typedef _Float16 f16x8 __attribute__((ext_vector_type(8)));
typedef float    f32x4 __attribute__((ext_vector_type(4)));

#define TBD 67108864ull   // T*B*D
#define BD  1048576ull    // B*D

#define ASM_VMCNT(N) asm volatile("s_waitcnt vmcnt(" #N ")" ::: "memory")
#define ASM_LGKM(N)  asm volatile("s_waitcnt lgkmcnt(" #N ")" ::: "memory")
#define BARRIER()    __builtin_amdgcn_s_barrier()
#define MFMA(a,b,c)  __builtin_amdgcn_mfma_f32_16x16x32_f16((a),(b),(c),0,0,0)

// ---------------- Kernel 1: se = (pred-true)^2 -> fp16 ----------------
__global__ __launch_bounds__(256) void se_split_k(const float* __restrict__ pred,
                                                  const float* __restrict__ tru,
                                                  _Float16* __restrict__ hi) {
  size_t stride = (size_t)gridDim.x * 1024;
  for (size_t i = ((size_t)blockIdx.x * 256 + threadIdx.x) * 4; i < TBD; i += stride) {
    float4 p = *(const float4*)(pred + i);
    float4 t = *(const float4*)(tru + i);
    f16x4 h;
    h[0] = (_Float16)((p.x - t.x) * (p.x - t.x));
    h[1] = (_Float16)((p.y - t.y) * (p.y - t.y));
    h[2] = (_Float16)((p.z - t.z) * (p.z - t.z));
    h[3] = (_Float16)((p.w - t.w) * (p.w - t.w));
    *(f16x4*)(hi + i) = h;
  }
}

// ---------------- Kernel 2: W -> fp16 ----------------
__global__ __launch_bounds__(256) void w_split_k(const float* __restrict__ W,
                                                 _Float16* __restrict__ hi) {
  size_t i = ((size_t)blockIdx.x * 256 + threadIdx.x) * 4;  // covers 1048576 exactly
  float4 x = *(const float4*)(W + i);
  f16x4 h;
  h[0] = (_Float16)x.x; h[1] = (_Float16)x.y; h[2] = (_Float16)x.z; h[3] = (_Float16)x.w;
  *(f16x4*)(hi + i) = h;
}

// ---------------- Kernel 3: logits(fp32) = SE @ Wh^T + b  (single-pass fp16 MFMA) -----
// M=65536, N=1024, K=1024. Block-tile 128x256, BK=32, 4 waves (2M x 2N),
// wave-tile 64x128. 3 blocks/CU (144KB LDS, launch_bounds(256,3)): 3-wave TLP/SIMD.
// C stays fp32: quarter-wave store segment = 16 lanes x 4B = 64B (HBM granularity).
//   [r10 lesson: fp16 C -> 32B segments -> 7x RMW write amplification, kernel 3.4x slower]
// LDS super-row layout (r9-verified 0 conflicts): srow = rows {2s,2s+1}, 128B = 8x16B
// slots; logical ls = kchunk + 4*(row&1); physical = ls ^ (srow&7).
// Buffer = A [64 srows][128B] (8KB) + B [128 srows][128B] (16KB) = 24KB; dbuf 48KB.
// K-loop (r3/r8 cadence): 12 ds_reads; lgkm(6/4/2/0) fences; all-reads barrier;
// stage 6 loads for t+2; counted vmcnt(6), never drained in the loop.

#define GL2_A(dstb, kof)                                                          \
  _Pragma("unroll")                                                               \
  for (int q = 0; q < 2; ++q)                                                     \
    __builtin_amdgcn_global_load_lds(                                             \
        (const __attribute__((address_space(1))) void*)(aSrc[q] + (kof)),         \
        (__attribute__((address_space(3))) void*)((dstb) + q * 4096 + tid * 16),  \
        16, 0, 0);

#define GL4_B(dstb, kof)                                                          \
  _Pragma("unroll")                                                               \
  for (int q = 0; q < 4; ++q)                                                     \
    __builtin_amdgcn_global_load_lds(                                             \
        (const __attribute__((address_space(1))) void*)(bSrc[q] + (kof)),         \
        (__attribute__((address_space(3))) void*)((dstb) + 8192 + q * 4096 + tid * 16), \
        16, 0, 0);

// 8 MFMAs per cluster: 8 independent accumulators (4 fi x 2 fj).
#define MCL(j0, B0, B1)                                  \
  __builtin_amdgcn_s_setprio(1);                         \
  acc[0][(j0)]   = MFMA(a0, B0, acc[0][(j0)]);           \
  acc[1][(j0)]   = MFMA(a1, B0, acc[1][(j0)]);           \
  acc[2][(j0)]   = MFMA(a2, B0, acc[2][(j0)]);           \
  acc[3][(j0)]   = MFMA(a3, B0, acc[3][(j0)]);           \
  acc[0][(j0)+1] = MFMA(a0, B1, acc[0][(j0)+1]);         \
  acc[1][(j0)+1] = MFMA(a1, B1, acc[1][(j0)+1]);         \
  acc[2][(j0)+1] = MFMA(a2, B1, acc[2][(j0)+1]);         \
  acc[3][(j0)+1] = MFMA(a3, B1, acc[3][(j0)+1]);         \
  __builtin_amdgcn_s_setprio(0);

#define LD(buf, off) (*(const f16x8*)((buf) + (off)))

__global__ __launch_bounds__(256, 3) void gemm_logits_k(
    const _Float16* __restrict__ Ah, const _Float16* __restrict__ Wh,
    const float* __restrict__ bias, float* __restrict__ C) {
  __shared__ uint4 lds4[3072];  // 48 KiB
  char* lds = (char*)lds4;
  const int tid = threadIdx.x;
  const int lane = tid & 63;
  const int wid = tid >> 6;          // 0..3
  const int wm = wid >> 1;           // 0..1 (M)
  const int wn = wid & 1;            // 0..1 (N)

  // XCD-aware bijective swizzle: 2048 blocks, 8 XCDs, 256 per XCD.
  const int bid = blockIdx.x;
  const int wgid = (bid & 7) * 256 + (bid >> 3);
  const int bm = wgid >> 2, bn = wgid & 3;   // 512 M-tiles x 4 N-tiles
  const int row0 = bm * 128, col0 = bn * 256;

  // Staging sources (inverse of the super-row swizzle). A: 2 chunks; B: 4 chunks.
  const _Float16* aSrc[2];
  const _Float16* bSrc[4];
#pragma unroll
  for (int q = 0; q < 2; ++q) {
    int p = q * 4096 + tid * 16;      // byte offset in A region (8KB)
    int srow = p >> 7;                // 0..63
    int s = (p >> 4) & 7;             // physical slot
    int sig = s ^ (srow & 7);         // logical slot
    int row = 2 * srow + (sig >> 2);
    aSrc[q] = Ah + ((size_t)(row0 + row) * 1024 + (size_t)(sig & 3) * 8);
  }
#pragma unroll
  for (int q = 0; q < 4; ++q) {
    int p = q * 4096 + tid * 16;      // byte offset in B region (16KB)
    int srow = p >> 7;                // 0..127
    int s = (p >> 4) & 7;
    int sig = s ^ (srow & 7);
    int row = 2 * srow + (sig >> 2);
    bSrc[q] = Wh + ((size_t)(col0 + row) * 1024 + (size_t)(sig & 3) * 8);
  }

  // Fragment read offsets. 16x16x32 A-op: lane -> row (lane&15), k-chunk u=lane>>4.
  const int u = lane >> 4;             // 0..3
  const int hr = (lane & 15) >> 1;     // srow low bits 0..7
  const int ls = u + 4 * (lane & 1);   // logical slot
  const int aoff = (wm * 32 + hr) * 128 + ((ls ^ hr) * 16);           // + fi*1024
  const int boff = 8192 + (wn * 64 + hr) * 128 + ((ls ^ hr) * 16);    // + fj*1024

  f32x4 acc[4][8] = {};

  // Prologue: tile 0 -> buf0, tile 1 -> buf1; vmcnt(6) -> tile 0 resident.
  char* buf0 = lds;
  char* buf1 = lds + 24576;
  GL2_A(buf0, 0)
  GL4_B(buf0, 0)
  GL2_A(buf1, 32)
  GL4_B(buf1, 32)
  ASM_VMCNT(6);
  BARRIER();

#pragma unroll 1
  for (int t = 0; t < 32; ++t) {
    char* ldsb = lds + (t & 1) * 24576;
    const int tt = (t + 2 < 32) ? t + 2 : 31;   // dummy tail reload keeps vmcnt cadence
    const size_t kof = (size_t)tt * 32;

    // 12 ds_reads: A (4) then B (8)
    f16x8 a0 = LD(ldsb, aoff + 0 * 1024);
    f16x8 a1 = LD(ldsb, aoff + 1 * 1024);
    f16x8 a2 = LD(ldsb, aoff + 2 * 1024);
    f16x8 a3 = LD(ldsb, aoff + 3 * 1024);
    f16x8 b0 = LD(ldsb, boff + 0 * 1024);
    f16x8 b1 = LD(ldsb, boff + 1 * 1024);
    f16x8 b2 = LD(ldsb, boff + 2 * 1024);
    f16x8 b3 = LD(ldsb, boff + 3 * 1024);
    f16x8 b4 = LD(ldsb, boff + 4 * 1024);
    f16x8 b5 = LD(ldsb, boff + 5 * 1024);
    f16x8 b6 = LD(ldsb, boff + 6 * 1024);
    f16x8 b7 = LD(ldsb, boff + 7 * 1024);
    ASM_LGKM(6);               // A + b0,b1 resident
    MCL(0, b0, b1)
    ASM_LGKM(4);               // b2,b3
    MCL(2, b2, b3)
    ASM_LGKM(2);               // b4,b5
    MCL(4, b4, b5)
    ASM_LGKM(0);               // all reads of ldsb done
    BARRIER();                 // every wave done reading -> safe to overwrite
    GL2_A(ldsb, kof)           // stage tile t+2 (6 loads)
    GL4_B(ldsb, kof)
    MCL(6, b6, b7)
    ASM_VMCNT(6);              // tile t+1's 6 loads landed (t+2's 6 in flight)
    BARRIER();
  }
  ASM_VMCNT(0);    // drain tail dummy loads

  // Epilogue: C[i,j] = acc + bias[j].  C/D: col=lane&15, row=(lane>>4)*4+q.
  // fp32 stores: 16-lane segment = 64B (aligned) -> no write amplification.
#pragma unroll
  for (int fj = 0; fj < 8; ++fj) {
    int c = col0 + wn * 128 + fj * 16 + (lane & 15);
    float bj = bias[c];
#pragma unroll
    for (int fi = 0; fi < 4; ++fi) {
      int r = row0 + wm * 64 + fi * 16 + u * 4;
#pragma unroll
      for (int q = 0; q < 4; ++q)
        C[(size_t)(r + q) * 1024 + c] = acc[fi][fj][q] + bj;
    }
  }
}

// ---------------- Kernel 4: fused softmax + gating + loss accumulation ----------------
__global__ __launch_bounds__(256) void softmax_loss_k(const float* __restrict__ logits,
                                                      const _Float16* __restrict__ hi,
                                                      float* __restrict__ out) {
  const int b = blockIdx.x;            // 0..1023
  const int tid = threadIdx.x, lane = tid & 63, wid = tid >> 6;
  __shared__ float red[8];
  float4 wprev = make_float4(1.f, 1.f, 1.f, 1.f);
  float4 lacc  = make_float4(0.f, 0.f, 0.f, 0.f);

  size_t base = (size_t)b * 1024;      // row (t=0, b)
  float4 x = ((const float4*)(logits + base))[tid];
  f16x4  h = ((const f16x4*)(hi + base))[tid];

#pragma unroll 1
  for (int t = 0; t < 64; ++t) {
    float4 se;
    se.x = (float)h[0];
    se.y = (float)h[1];
    se.z = (float)h[2];
    se.w = (float)h[3];
    lacc.x += wprev.x * se.x;
    lacc.y += wprev.y * se.y;
    lacc.z += wprev.z * se.z;
    lacc.w += wprev.w * se.w;

    int tn = (t + 1 < 64) ? t + 1 : t;
    size_t nbase = ((size_t)tn * 1024 + (size_t)b) * 1024;
    float4 xn = ((const float4*)(logits + nbase))[tid];
    f16x4  hn = ((const f16x4*)(hi + nbase))[tid];

    float m = fmaxf(fmaxf(x.x, x.y), fmaxf(x.z, x.w));
#pragma unroll
    for (int o = 32; o >= 1; o >>= 1) m = fmaxf(m, __shfl_xor(m, o, 64));
    if (lane == 0) red[wid] = m;
    __syncthreads();
    m = fmaxf(fmaxf(red[0], red[1]), fmaxf(red[2], red[3]));
    float e0 = __expf(x.x - m), e1 = __expf(x.y - m), e2 = __expf(x.z - m), e3 = __expf(x.w - m);
    float s = (e0 + e1) + (e2 + e3);
#pragma unroll
    for (int o = 32; o >= 1; o >>= 1) s += __shfl_xor(s, o, 64);
    if (lane == 0) red[4 + wid] = s;
    __syncthreads();
    s = (red[4] + red[5]) + (red[6] + red[7]);
    float inv = 1.0f / s;

    wprev.x = se.x * e0 * inv;
    wprev.y = se.y * e1 * inv;
    wprev.z = se.z * e2 * inv;
    wprev.w = se.w * e3 * inv;

    x = xn; h = hn;
  }
  ((float4*)(out + (size_t)b * 1024))[tid] = lacc;
}

extern "C" void kernel_launch(void* const* d_in, const int* in_sizes, int n_in,
                              void* d_out, int out_size, void* d_ws, size_t ws_size,
                              hipStream_t stream) {
  const float* pred = (const float*)d_in[0];
  const float* tru  = (const float*)d_in[1];
  const float* W    = (const float*)d_in[2];
  const float* bias = (const float*)d_in[3];
  float* out = (float*)d_out;

  char* ws = (char*)d_ws;
  _Float16* se_hi  = (_Float16*)(ws);                    // 128 MB
  float*    logits = (float*)   (ws + 134217728ull);     // 256 MB (fp32)
  _Float16* W_hi   = (_Float16*)(ws + 402653184ull);     // 2 MB

  se_split_k<<<2048, 256, 0, stream>>>(pred, tru, se_hi);
  w_split_k<<<1024, 256, 0, stream>>>(W, W_hi);
  gemm_logits_k<<<2048, 256, 0, stream>>>(se_hi, W_hi, bias, logits);
  softmax_loss_k<<<1024, 256, 0, stream>>>(logits, se_hi, out);
}

// Round 12
// 379.027 us; speedup vs baseline: 2.1840x; 2.1840x over previous
//
#include <hip/hip_runtime.h>
#include <hip/hip_fp16.h>

typedef _Float16 f16x4 __attribute__((ext_vector_type(4)));
typedef _Float16 f16x8 __attribute__((ext_vector_type(8)));
typedef float    f32x4 __attribute__((ext_vector_type(4)));

#define TBD 67108864ull   // T*B*D
#define BD  1048576ull    // B*D

#define ASM_VMCNT(N) asm volatile("s_waitcnt vmcnt(" #N ")" ::: "memory")
#define ASM_LGKM(N)  asm volatile("s_waitcnt lgkmcnt(" #N ")" ::: "memory")
#define BARRIER()    __builtin_amdgcn_s_barrier()
#define MFMA(a,b,c)  __builtin_amdgcn_mfma_f32_16x16x32_f16((a),(b),(c),0,0,0)

// ---------------- Kernel 1: se = (pred-true)^2 -> fp16 ; blocks 0-1023 also cast W ----
__global__ __launch_bounds__(256) void se_split_k(const float* __restrict__ pred,
                                                  const float* __restrict__ tru,
                                                  const float* __restrict__ W,
                                                  _Float16* __restrict__ hi,
                                                  _Float16* __restrict__ W_hi) {
  if (blockIdx.x < 1024) {   // fold W cast: 1024 blk x 256 thr x 4 = 1M elems exactly
    size_t wi = ((size_t)blockIdx.x * 256 + threadIdx.x) * 4;
    float4 x = *(const float4*)(W + wi);
    f16x4 h;
    h[0] = (_Float16)x.x; h[1] = (_Float16)x.y; h[2] = (_Float16)x.z; h[3] = (_Float16)x.w;
    *(f16x4*)(W_hi + wi) = h;
  }
  size_t stride = (size_t)gridDim.x * 1024;
  for (size_t i = ((size_t)blockIdx.x * 256 + threadIdx.x) * 4; i < TBD; i += stride) {
    float4 p = *(const float4*)(pred + i);
    float4 t = *(const float4*)(tru + i);
    f16x4 h;
    h[0] = (_Float16)((p.x - t.x) * (p.x - t.x));
    h[1] = (_Float16)((p.y - t.y) * (p.y - t.y));
    h[2] = (_Float16)((p.z - t.z) * (p.z - t.z));
    h[3] = (_Float16)((p.w - t.w) * (p.w - t.w));
    *(f16x4*)(hi + i) = h;
  }
}

// ---------------- Kernel 2: logits(fp32) = SE @ Wh^T + b  (single-pass fp16 MFMA) -----
// M=65536, N=1024, K=1024. Block-tile 128x256, BK=32, 4 waves (2M x 2N),
// wave-tile 64x128. __launch_bounds__(256,2): 2 blocks/CU -- r9-verified best.
//   [r10/r11 lesson: 3 blocks/CU triples the in-flight C-tile write footprint past
//    L2 (12MB vs 4MB/XCD) -> partial 64B-half line evictions -> 4x HBM write
//    amplification (271MB->1.06GB) -> kernel goes write-bound. Keep occupancy 2.]
// C stays fp32: 16-lane store segment = 64B (r9 WRITE_SIZE clean at 271MB).
// LDS super-row layout (r9-verified 0 conflicts): srow = rows {2s,2s+1}, 128B = 8x16B
// slots; logical ls = kchunk + 4*(row&1); physical = ls ^ (srow&7).
// Buffer = A [64 srows][128B] (8KB) + B [128 srows][128B] (16KB) = 24KB; dbuf 48KB.
// K-loop (r3/r8 cadence): 12 ds_reads; lgkm(6/4/2/0) fences; all-reads barrier;
// stage 6 loads for t+2; counted vmcnt(6), never drained in the loop.

#define GL2_A(dstb, kof)                                                          \
  _Pragma("unroll")                                                               \
  for (int q = 0; q < 2; ++q)                                                     \
    __builtin_amdgcn_global_load_lds(                                             \
        (const __attribute__((address_space(1))) void*)(aSrc[q] + (kof)),         \
        (__attribute__((address_space(3))) void*)((dstb) + q * 4096 + tid * 16),  \
        16, 0, 0);

#define GL4_B(dstb, kof)                                                          \
  _Pragma("unroll")                                                               \
  for (int q = 0; q < 4; ++q)                                                     \
    __builtin_amdgcn_global_load_lds(                                             \
        (const __attribute__((address_space(1))) void*)(bSrc[q] + (kof)),         \
        (__attribute__((address_space(3))) void*)((dstb) + 8192 + q * 4096 + tid * 16), \
        16, 0, 0);

// 8 MFMAs per cluster: 8 independent accumulators (4 fi x 2 fj).
#define MCL(j0, B0, B1)                                  \
  __builtin_amdgcn_s_setprio(1);                         \
  acc[0][(j0)]   = MFMA(a0, B0, acc[0][(j0)]);           \
  acc[1][(j0)]   = MFMA(a1, B0, acc[1][(j0)]);           \
  acc[2][(j0)]   = MFMA(a2, B0, acc[2][(j0)]);           \
  acc[3][(j0)]   = MFMA(a3, B0, acc[3][(j0)]);           \
  acc[0][(j0)+1] = MFMA(a0, B1, acc[0][(j0)+1]);         \
  acc[1][(j0)+1] = MFMA(a1, B1, acc[1][(j0)+1]);         \
  acc[2][(j0)+1] = MFMA(a2, B1, acc[2][(j0)+1]);         \
  acc[3][(j0)+1] = MFMA(a3, B1, acc[3][(j0)+1]);         \
  __builtin_amdgcn_s_setprio(0);

#define LD(buf, off) (*(const f16x8*)((buf) + (off)))

__global__ __launch_bounds__(256, 2) void gemm_logits_k(
    const _Float16* __restrict__ Ah, const _Float16* __restrict__ Wh,
    const float* __restrict__ bias, float* __restrict__ C) {
  __shared__ uint4 lds4[3072];  // 48 KiB
  char* lds = (char*)lds4;
  const int tid = threadIdx.x;
  const int lane = tid & 63;
  const int wid = tid >> 6;          // 0..3
  const int wm = wid >> 1;           // 0..1 (M)
  const int wn = wid & 1;            // 0..1 (N)

  // XCD-aware bijective swizzle: 2048 blocks, 8 XCDs, 256 per XCD.
  const int bid = blockIdx.x;
  const int wgid = (bid & 7) * 256 + (bid >> 3);
  const int bm = wgid >> 2, bn = wgid & 3;   // 512 M-tiles x 4 N-tiles
  const int row0 = bm * 128, col0 = bn * 256;

  // Staging sources (inverse of the super-row swizzle). A: 2 chunks; B: 4 chunks.
  const _Float16* aSrc[2];
  const _Float16* bSrc[4];
#pragma unroll
  for (int q = 0; q < 2; ++q) {
    int p = q * 4096 + tid * 16;      // byte offset in A region (8KB)
    int srow = p >> 7;                // 0..63
    int s = (p >> 4) & 7;             // physical slot
    int sig = s ^ (srow & 7);         // logical slot
    int row = 2 * srow + (sig >> 2);
    aSrc[q] = Ah + ((size_t)(row0 + row) * 1024 + (size_t)(sig & 3) * 8);
  }
#pragma unroll
  for (int q = 0; q < 4; ++q) {
    int p = q * 4096 + tid * 16;      // byte offset in B region (16KB)
    int srow = p >> 7;                // 0..127
    int s = (p >> 4) & 7;
    int sig = s ^ (srow & 7);
    int row = 2 * srow + (sig >> 2);
    bSrc[q] = Wh + ((size_t)(col0 + row) * 1024 + (size_t)(sig & 3) * 8);
  }

  // Fragment read offsets. 16x16x32 A-op: lane -> row (lane&15), k-chunk u=lane>>4.
  const int u = lane >> 4;             // 0..3
  const int hr = (lane & 15) >> 1;     // srow low bits 0..7
  const int ls = u + 4 * (lane & 1);   // logical slot
  const int aoff = (wm * 32 + hr) * 128 + ((ls ^ hr) * 16);           // + fi*1024
  const int boff = 8192 + (wn * 64 + hr) * 128 + ((ls ^ hr) * 16);    // + fj*1024

  f32x4 acc[4][8] = {};

  // Prologue: tile 0 -> buf0, tile 1 -> buf1; vmcnt(6) -> tile 0 resident.
  char* buf0 = lds;
  char* buf1 = lds + 24576;
  GL2_A(buf0, 0)
  GL4_B(buf0, 0)
  GL2_A(buf1, 32)
  GL4_B(buf1, 32)
  ASM_VMCNT(6);
  BARRIER();

#pragma unroll 1
  for (int t = 0; t < 32; ++t) {
    char* ldsb = lds + (t & 1) * 24576;
    const int tt = (t + 2 < 32) ? t + 2 : 31;   // dummy tail reload keeps vmcnt cadence
    const size_t kof = (size_t)tt * 32;

    // 12 ds_reads: A (4) then B (8)
    f16x8 a0 = LD(ldsb, aoff + 0 * 1024);
    f16x8 a1 = LD(ldsb, aoff + 1 * 1024);
    f16x8 a2 = LD(ldsb, aoff + 2 * 1024);
    f16x8 a3 = LD(ldsb, aoff + 3 * 1024);
    f16x8 b0 = LD(ldsb, boff + 0 * 1024);
    f16x8 b1 = LD(ldsb, boff + 1 * 1024);
    f16x8 b2 = LD(ldsb, boff + 2 * 1024);
    f16x8 b3 = LD(ldsb, boff + 3 * 1024);
    f16x8 b4 = LD(ldsb, boff + 4 * 1024);
    f16x8 b5 = LD(ldsb, boff + 5 * 1024);
    f16x8 b6 = LD(ldsb, boff + 6 * 1024);
    f16x8 b7 = LD(ldsb, boff + 7 * 1024);
    ASM_LGKM(6);               // A + b0,b1 resident
    MCL(0, b0, b1)
    ASM_LGKM(4);               // b2,b3
    MCL(2, b2, b3)
    ASM_LGKM(2);               // b4,b5
    MCL(4, b4, b5)
    ASM_LGKM(0);               // all reads of ldsb done
    BARRIER();                 // every wave done reading -> safe to overwrite
    GL2_A(ldsb, kof)           // stage tile t+2 (6 loads)
    GL4_B(ldsb, kof)
    MCL(6, b6, b7)
    ASM_VMCNT(6);              // tile t+1's 6 loads landed (t+2's 6 in flight)
    BARRIER();
  }
  ASM_VMCNT(0);    // drain tail dummy loads

  // Epilogue: C[i,j] = acc + bias[j].  C/D: col=lane&15, row=(lane>>4)*4+q.
  // fp32 stores: 16-lane segment = 64B (aligned) -> clean HBM writes (r9-verified).
#pragma unroll
  for (int fj = 0; fj < 8; ++fj) {
    int c = col0 + wn * 128 + fj * 16 + (lane & 15);
    float bj = bias[c];
#pragma unroll
    for (int fi = 0; fi < 4; ++fi) {
      int r = row0 + wm * 64 + fi * 16 + u * 4;
#pragma unroll
      for (int q = 0; q < 4; ++q)
        C[(size_t)(r + q) * 1024 + c] = acc[fi][fj][q] + bj;
    }
  }
}

// ---------------- Kernel 3: fused softmax + gating + loss accumulation ----------------
__global__ __launch_bounds__(256) void softmax_loss_k(const float* __restrict__ logits,
                                                      const _Float16* __restrict__ hi,
                                                      float* __restrict__ out) {
  const int b = blockIdx.x;            // 0..1023
  const int tid = threadIdx.x, lane = tid & 63, wid = tid >> 6;
  __shared__ float red[8];
  float4 wprev = make_float4(1.f, 1.f, 1.f, 1.f);
  float4 lacc  = make_float4(0.f, 0.f, 0.f, 0.f);

  size_t base = (size_t)b * 1024;      // row (t=0, b)
  float4 x = ((const float4*)(logits + base))[tid];
  f16x4  h = ((const f16x4*)(hi + base))[tid];

#pragma unroll 1
  for (int t = 0; t < 64; ++t) {
    float4 se;
    se.x = (float)h[0];
    se.y = (float)h[1];
    se.z = (float)h[2];
    se.w = (float)h[3];
    lacc.x += wprev.x * se.x;
    lacc.y += wprev.y * se.y;
    lacc.z += wprev.z * se.z;
    lacc.w += wprev.w * se.w;

    int tn = (t + 1 < 64) ? t + 1 : t;
    size_t nbase = ((size_t)tn * 1024 + (size_t)b) * 1024;
    float4 xn = ((const float4*)(logits + nbase))[tid];
    f16x4  hn = ((const f16x4*)(hi + nbase))[tid];

    float m = fmaxf(fmaxf(x.x, x.y), fmaxf(x.z, x.w));
#pragma unroll
    for (int o = 32; o >= 1; o >>= 1) m = fmaxf(m, __shfl_xor(m, o, 64));
    if (lane == 0) red[wid] = m;
    __syncthreads();
    m = fmaxf(fmaxf(red[0], red[1]), fmaxf(red[2], red[3]));
    float e0 = __expf(x.x - m), e1 = __expf(x.y - m), e2 = __expf(x.z - m), e3 = __expf(x.w - m);
    float s = (e0 + e1) + (e2 + e3);
#pragma unroll
    for (int o = 32; o >= 1; o >>= 1) s += __shfl_xor(s, o, 64);
    if (lane == 0) red[4 + wid] = s;
    __syncthreads();
    s = (red[4] + red[5]) + (red[6] + red[7]);
    float inv = 1.0f / s;

    wprev.x = se.x * e0 * inv;
    wprev.y = se.y * e1 * inv;
    wprev.z = se.z * e2 * inv;
    wprev.w = se.w * e3 * inv;

    x = xn; h = hn;
  }
  ((float4*)(out + (size_t)b * 1024))[tid] = lacc;
}

extern "C" void kernel_launch(void* const* d_in, const int* in_sizes, int n_in,
                              void* d_out, int out_size, void* d_ws, size_t ws_size,
                              hipStream_t stream) {
  const float* pred = (const float*)d_in[0];
  const float* tru  = (const float*)d_in[1];
  const float* W    = (const float*)d_in[2];
  const float* bias = (const float*)d_in[3];
  float* out = (float*)d_out;

  char* ws = (char*)d_ws;
  _Float16* se_hi  = (_Float16*)(ws);                    // 128 MB
  float*    logits = (float*)   (ws + 134217728ull);     // 256 MB (fp32)
  _Float16* W_hi   = (_Float16*)(ws + 402653184ull);     // 2 MB

  se_split_k<<<2048, 256, 0, stream>>>(pred, tru, W, se_hi, W_hi);
  gemm_logits_k<<<2048, 256, 0, stream>>>(se_hi, W_hi, bias, logits);
  softmax_loss_k<<<1024, 256, 0, stream>>>(logits, se_hi, out);
}

// Round 13
// 334.863 us; speedup vs baseline: 2.4720x; 1.1319x over previous
//
#include <hip/hip_runtime.h>
#include <hip/hip_fp16.h>

typedef _Float16 f16x2 __attribute__((ext_vector_type(2)));
typedef _Float16 f16x4 __attribute__((ext_vector_type(4)));
typedef _Float16 f16x8 __attribute__((ext_vector_type(8)));
typedef float    f32x4 __attribute__((ext_vector_type(4)));

#define TBD 67108864ull   // T*B*D
#define BD  1048576ull    // B*D

#define ASM_VMCNT(N) asm volatile("s_waitcnt vmcnt(" #N ")" ::: "memory")
#define ASM_LGKM(N)  asm volatile("s_waitcnt lgkmcnt(" #N ")" ::: "memory")
#define BARRIER()    __builtin_amdgcn_s_barrier()
#define MFMA(a,b,c)  __builtin_amdgcn_mfma_f32_16x16x32_f16((a),(b),(c),0,0,0)

// ---------------- Kernel 1: se = (pred-true)^2 -> fp16 ; blocks 0-1023 also cast W ----
// 8 floats/thread/iter (2x float4 per stream, f16x8 store): 2x MLP vs r12.
__global__ __launch_bounds__(256) void se_split_k(const float* __restrict__ pred,
                                                  const float* __restrict__ tru,
                                                  const float* __restrict__ W,
                                                  _Float16* __restrict__ hi,
                                                  _Float16* __restrict__ W_hi) {
  if (blockIdx.x < 1024) {   // fold W cast: 1024 blk x 256 thr x 4 = 1M elems exactly
    size_t wi = ((size_t)blockIdx.x * 256 + threadIdx.x) * 4;
    float4 x = *(const float4*)(W + wi);
    f16x4 h;
    h[0] = (_Float16)x.x; h[1] = (_Float16)x.y; h[2] = (_Float16)x.z; h[3] = (_Float16)x.w;
    *(f16x4*)(W_hi + wi) = h;
  }
  size_t stride = (size_t)gridDim.x * 2048;   // 256 thr x 8 elems
  for (size_t i = ((size_t)blockIdx.x * 256 + threadIdx.x) * 8; i < TBD; i += stride) {
    float4 p0 = *(const float4*)(pred + i);
    float4 p1 = *(const float4*)(pred + i + 4);
    float4 t0 = *(const float4*)(tru + i);
    float4 t1 = *(const float4*)(tru + i + 4);
    f16x8 h;
    h[0] = (_Float16)((p0.x - t0.x) * (p0.x - t0.x));
    h[1] = (_Float16)((p0.y - t0.y) * (p0.y - t0.y));
    h[2] = (_Float16)((p0.z - t0.z) * (p0.z - t0.z));
    h[3] = (_Float16)((p0.w - t0.w) * (p0.w - t0.w));
    h[4] = (_Float16)((p1.x - t1.x) * (p1.x - t1.x));
    h[5] = (_Float16)((p1.y - t1.y) * (p1.y - t1.y));
    h[6] = (_Float16)((p1.z - t1.z) * (p1.z - t1.z));
    h[7] = (_Float16)((p1.w - t1.w) * (p1.w - t1.w));
    *(f16x8*)(hi + i) = h;
  }
}

// ---------------- Kernel 2: logits16 = pack16(SE @ Wh^T + b)  ----------------
// Same GEMM core as r9/r12 (verified 176us, 0 conflicts, clean writes, (256,2)).
// NEW epilogue: fp16 logits packed as u32 per column-PAIR (c, c+64) within each
// 128-col span -> 16-lane store segment = 64B (r10 lesson: naive fp16 = 32B
// segments = 7x RMW write amplification; this packing keeps fp32's clean 64B).
// logits16 layout: u32 L[row][512]; L[row][s*64 + x] = {fp16 logit[s*128+x],
// fp16 logit[s*128+x+64]}, s = span 0..7, x = 0..63. Softmax is column-
// permutation-invariant; consumer remaps se/out accesses with the same map.

#define GL2_A(dstb, kof)                                                          \
  _Pragma("unroll")                                                               \
  for (int q = 0; q < 2; ++q)                                                     \
    __builtin_amdgcn_global_load_lds(                                             \
        (const __attribute__((address_space(1))) void*)(aSrc[q] + (kof)),         \
        (__attribute__((address_space(3))) void*)((dstb) + q * 4096 + tid * 16),  \
        16, 0, 0);

#define GL4_B(dstb, kof)                                                          \
  _Pragma("unroll")                                                               \
  for (int q = 0; q < 4; ++q)                                                     \
    __builtin_amdgcn_global_load_lds(                                             \
        (const __attribute__((address_space(1))) void*)(bSrc[q] + (kof)),         \
        (__attribute__((address_space(3))) void*)((dstb) + 8192 + q * 4096 + tid * 16), \
        16, 0, 0);

#define MCL(j0, B0, B1)                                  \
  __builtin_amdgcn_s_setprio(1);                         \
  acc[0][(j0)]   = MFMA(a0, B0, acc[0][(j0)]);           \
  acc[1][(j0)]   = MFMA(a1, B0, acc[1][(j0)]);           \
  acc[2][(j0)]   = MFMA(a2, B0, acc[2][(j0)]);           \
  acc[3][(j0)]   = MFMA(a3, B0, acc[3][(j0)]);           \
  acc[0][(j0)+1] = MFMA(a0, B1, acc[0][(j0)+1]);         \
  acc[1][(j0)+1] = MFMA(a1, B1, acc[1][(j0)+1]);         \
  acc[2][(j0)+1] = MFMA(a2, B1, acc[2][(j0)+1]);         \
  acc[3][(j0)+1] = MFMA(a3, B1, acc[3][(j0)+1]);         \
  __builtin_amdgcn_s_setprio(0);

#define LD(buf, off) (*(const f16x8*)((buf) + (off)))

__global__ __launch_bounds__(256, 2) void gemm_logits_k(
    const _Float16* __restrict__ Ah, const _Float16* __restrict__ Wh,
    const float* __restrict__ bias, unsigned int* __restrict__ C16) {
  __shared__ uint4 lds4[3072];  // 48 KiB
  char* lds = (char*)lds4;
  const int tid = threadIdx.x;
  const int lane = tid & 63;
  const int wid = tid >> 6;          // 0..3
  const int wm = wid >> 1;           // 0..1 (M)
  const int wn = wid & 1;            // 0..1 (N)

  // XCD-aware bijective swizzle: 2048 blocks, 8 XCDs, 256 per XCD.
  const int bid = blockIdx.x;
  const int wgid = (bid & 7) * 256 + (bid >> 3);
  const int bm = wgid >> 2, bn = wgid & 3;   // 512 M-tiles x 4 N-tiles
  const int row0 = bm * 128, col0 = bn * 256;

  // Staging sources (inverse of the super-row swizzle). A: 2 chunks; B: 4 chunks.
  const _Float16* aSrc[2];
  const _Float16* bSrc[4];
#pragma unroll
  for (int q = 0; q < 2; ++q) {
    int p = q * 4096 + tid * 16;      // byte offset in A region (8KB)
    int srow = p >> 7;                // 0..63
    int s = (p >> 4) & 7;             // physical slot
    int sig = s ^ (srow & 7);         // logical slot
    int row = 2 * srow + (sig >> 2);
    aSrc[q] = Ah + ((size_t)(row0 + row) * 1024 + (size_t)(sig & 3) * 8);
  }
#pragma unroll
  for (int q = 0; q < 4; ++q) {
    int p = q * 4096 + tid * 16;      // byte offset in B region (16KB)
    int srow = p >> 7;                // 0..127
    int s = (p >> 4) & 7;
    int sig = s ^ (srow & 7);
    int row = 2 * srow + (sig >> 2);
    bSrc[q] = Wh + ((size_t)(col0 + row) * 1024 + (size_t)(sig & 3) * 8);
  }

  // Fragment read offsets. 16x16x32 A-op: lane -> row (lane&15), k-chunk u=lane>>4.
  const int u = lane >> 4;             // 0..3
  const int hr = (lane & 15) >> 1;     // srow low bits 0..7
  const int ls = u + 4 * (lane & 1);   // logical slot
  const int aoff = (wm * 32 + hr) * 128 + ((ls ^ hr) * 16);           // + fi*1024
  const int boff = 8192 + (wn * 64 + hr) * 128 + ((ls ^ hr) * 16);    // + fj*1024

  f32x4 acc[4][8] = {};

  // Prologue: tile 0 -> buf0, tile 1 -> buf1; vmcnt(6) -> tile 0 resident.
  char* buf0 = lds;
  char* buf1 = lds + 24576;
  GL2_A(buf0, 0)
  GL4_B(buf0, 0)
  GL2_A(buf1, 32)
  GL4_B(buf1, 32)
  ASM_VMCNT(6);
  BARRIER();

#pragma unroll 1
  for (int t = 0; t < 32; ++t) {
    char* ldsb = lds + (t & 1) * 24576;
    const int tt = (t + 2 < 32) ? t + 2 : 31;   // dummy tail reload keeps vmcnt cadence
    const size_t kof = (size_t)tt * 32;

    // 12 ds_reads: A (4) then B (8)
    f16x8 a0 = LD(ldsb, aoff + 0 * 1024);
    f16x8 a1 = LD(ldsb, aoff + 1 * 1024);
    f16x8 a2 = LD(ldsb, aoff + 2 * 1024);
    f16x8 a3 = LD(ldsb, aoff + 3 * 1024);
    f16x8 b0 = LD(ldsb, boff + 0 * 1024);
    f16x8 b1 = LD(ldsb, boff + 1 * 1024);
    f16x8 b2 = LD(ldsb, boff + 2 * 1024);
    f16x8 b3 = LD(ldsb, boff + 3 * 1024);
    f16x8 b4 = LD(ldsb, boff + 4 * 1024);
    f16x8 b5 = LD(ldsb, boff + 5 * 1024);
    f16x8 b6 = LD(ldsb, boff + 6 * 1024);
    f16x8 b7 = LD(ldsb, boff + 7 * 1024);
    ASM_LGKM(6);               // A + b0,b1 resident
    MCL(0, b0, b1)
    ASM_LGKM(4);               // b2,b3
    MCL(2, b2, b3)
    ASM_LGKM(2);               // b4,b5
    MCL(4, b4, b5)
    ASM_LGKM(0);               // all reads of ldsb done
    BARRIER();                 // every wave done reading -> safe to overwrite
    GL2_A(ldsb, kof)           // stage tile t+2 (6 loads)
    GL4_B(ldsb, kof)
    MCL(6, b6, b7)
    ASM_VMCNT(6);              // tile t+1's 6 loads landed (t+2's 6 in flight)
    BARRIER();
  }
  ASM_VMCNT(0);    // drain tail dummy loads

  // Epilogue: packed fp16 pairs (c, c+64). 16-lane u32 stores = 64B segments.
  const int span = (col0 + wn * 128) >> 7;   // global 128-col span index 0..7
#pragma unroll
  for (int fj = 0; fj < 4; ++fj) {
    int x = fj * 16 + (lane & 15);           // pair index within span [0,64)
    int cl = col0 + wn * 128 + x;
    float bjl = bias[cl];
    float bjh = bias[cl + 64];
#pragma unroll
    for (int fi = 0; fi < 4; ++fi) {
      int r = row0 + wm * 64 + fi * 16 + u * 4;
#pragma unroll
      for (int q = 0; q < 4; ++q) {
        f16x2 v;
        v[0] = (_Float16)(acc[fi][fj][q] + bjl);
        v[1] = (_Float16)(acc[fi][fj + 4][q] + bjh);
        C16[(size_t)(r + q) * 512 + span * 64 + x] = __builtin_bit_cast(unsigned int, v);
      }
    }
  }
}

// ---------------- Kernel 3: fused softmax + gating + loss (packed fp16 logits) --------
// Thread tid owns u32 indices {2tid, 2tid+1} of each row -> logical cols
// {C+0, C+1, C+64, C+65} with C = (tid>>5)*128 + ((2*tid)&63). Softmax is
// permutation-invariant; se reads and out writes use the same mapping.
__global__ __launch_bounds__(256) void softmax_loss_k(const unsigned int* __restrict__ L16,
                                                      const _Float16* __restrict__ hi,
                                                      float* __restrict__ out) {
  const int b = blockIdx.x;            // 0..1023
  const int tid = threadIdx.x, lane = tid & 63, wid = tid >> 6;
  __shared__ float red[8];
  const int cA = (tid >> 5) * 128 + ((2 * tid) & 63);  // cols cA, cA+1
  const int cB = cA + 64;                               // cols cB, cB+1

  float4 wprev = make_float4(1.f, 1.f, 1.f, 1.f);   // order: cA, cA+1, cB, cB+1
  float4 lacc  = make_float4(0.f, 0.f, 0.f, 0.f);

  size_t base = (size_t)b * 1024;      // row (t=0, b)
  uint2 lg  = *(const uint2*)(L16 + (size_t)b * 512 + 2 * tid);
  f16x2 sA  = *(const f16x2*)(hi + base + cA);
  f16x2 sB  = *(const f16x2*)(hi + base + cB);

#pragma unroll 1
  for (int t = 0; t < 64; ++t) {
    float4 se;                          // cA, cA+1, cB, cB+1
    f16x2 p0 = __builtin_bit_cast(f16x2, lg.x);   // {col cA,   col cB}
    f16x2 p1 = __builtin_bit_cast(f16x2, lg.y);   // {col cA+1, col cB+1}
    se.x = (float)sA[0]; se.y = (float)sA[1];
    se.z = (float)sB[0]; se.w = (float)sB[1];
    lacc.x += wprev.x * se.x;
    lacc.y += wprev.y * se.y;
    lacc.z += wprev.z * se.z;
    lacc.w += wprev.w * se.w;

    int tn = (t + 1 < 64) ? t + 1 : t;
    size_t nrow = (size_t)tn * 1024 + (size_t)b;
    uint2 lgn = *(const uint2*)(L16 + nrow * 512 + 2 * tid);
    f16x2 sAn = *(const f16x2*)(hi + nrow * 1024 + cA);
    f16x2 sBn = *(const f16x2*)(hi + nrow * 1024 + cB);

    float xA0 = (float)p0[0], xB0 = (float)p0[1];
    float xA1 = (float)p1[0], xB1 = (float)p1[1];
    float m = fmaxf(fmaxf(xA0, xA1), fmaxf(xB0, xB1));
#pragma unroll
    for (int o = 32; o >= 1; o >>= 1) m = fmaxf(m, __shfl_xor(m, o, 64));
    if (lane == 0) red[wid] = m;
    __syncthreads();
    m = fmaxf(fmaxf(red[0], red[1]), fmaxf(red[2], red[3]));
    float e0 = __expf(xA0 - m), e1 = __expf(xA1 - m), e2 = __expf(xB0 - m), e3 = __expf(xB1 - m);
    float s = (e0 + e1) + (e2 + e3);
#pragma unroll
    for (int o = 32; o >= 1; o >>= 1) s += __shfl_xor(s, o, 64);
    if (lane == 0) red[4 + wid] = s;
    __syncthreads();
    s = (red[4] + red[5]) + (red[6] + red[7]);
    float inv = 1.0f / s;

    wprev.x = se.x * e0 * inv;
    wprev.y = se.y * e1 * inv;
    wprev.z = se.z * e2 * inv;
    wprev.w = se.w * e3 * inv;

    lg = lgn; sA = sAn; sB = sBn;
  }
  float2 oA = make_float2(lacc.x, lacc.y);
  float2 oB = make_float2(lacc.z, lacc.w);
  *(float2*)(out + (size_t)b * 1024 + cA) = oA;
  *(float2*)(out + (size_t)b * 1024 + cB) = oB;
}

extern "C" void kernel_launch(void* const* d_in, const int* in_sizes, int n_in,
                              void* d_out, int out_size, void* d_ws, size_t ws_size,
                              hipStream_t stream) {
  const float* pred = (const float*)d_in[0];
  const float* tru  = (const float*)d_in[1];
  const float* W    = (const float*)d_in[2];
  const float* bias = (const float*)d_in[3];
  float* out = (float*)d_out;

  char* ws = (char*)d_ws;
  _Float16*     se_hi = (_Float16*)(ws);                     // 128 MB
  unsigned int* L16   = (unsigned int*)(ws + 134217728ull);  // 128 MB (packed fp16)
  _Float16*     W_hi  = (_Float16*)(ws + 268435456ull);      // 2 MB

  se_split_k<<<2048, 256, 0, stream>>>(pred, tru, W, se_hi, W_hi);
  gemm_logits_k<<<2048, 256, 0, stream>>>(se_hi, W_hi, bias, L16);
  softmax_loss_k<<<1024, 256, 0, stream>>>(L16, se_hi, out);
}